// Round 5
// baseline (388.839 us; speedup 1.0000x reference)
//
#include <hip/hip_runtime.h>
#include <stdint.h>

#define B_ 8
#define N_ 2048
#define D_ 120
#define DP 128          // D padded to 128 (k-dim of MFMA)
#define QB 16           // q rows per block in attention kernel

typedef __attribute__((ext_vector_type(8))) short short8;
typedef __attribute__((ext_vector_type(4))) float f32x4;
typedef __attribute__((ext_vector_type(2))) float f32x2;
typedef __attribute__((ext_vector_type(4))) float float4v;
typedef __attribute__((ext_vector_type(4))) unsigned int u32x4;
typedef unsigned short u16;
typedef unsigned int u32;

// f32 -> bf16 (RNE) and back, bit-level (all values finite here)
__device__ __forceinline__ u16 f2bf(float f){
    union { float f; uint32_t u; } v; v.f = f;
    uint32_t u = v.u;
    return (u16)((u + 0x7fffu + ((u >> 16) & 1u)) >> 16);
}
__device__ __forceinline__ float bf2f(u16 h){
    union { uint32_t u; float f; } v; v.u = ((uint32_t)h) << 16; return v.f;
}

__device__ __forceinline__ f32x4 mfma16(short8 a, short8 b, f32x4 c){
    return __builtin_amdgcn_mfma_f32_16x16x32_bf16(a, b, c, 0, 0, 0);
}

// ---------------------------------------------------------------------------
// Kernel 0: transpose + split weights. Wt[c][d] (bf16 hi/lo), zero-padded to
// 128x128. Scale 1/sqrt(D) folded into W_query.
// ---------------------------------------------------------------------------
__global__ void wprep(const float* __restrict__ Wq, const float* __restrict__ Wk,
                      const float* __restrict__ Wv,
                      u16* __restrict__ Wth, u16* __restrict__ Wtl){
    int p = blockIdx.x;
    const float* W = (p == 0) ? Wq : (p == 1 ? Wk : Wv);
    float scale = (p == 0) ? 0.09128709291752768f : 1.0f;  // 1/sqrt(120)
    for (int idx = threadIdx.x; idx < DP * DP; idx += blockDim.x){
        int c = idx & (DP - 1);
        int d = idx >> 7;
        float w = (c < D_ && d < D_) ? W[d * D_ + c] * scale : 0.f;
        u16 hi = f2bf(w);
        Wth[p * DP * DP + c * DP + d] = hi;
        Wtl[p * DP * DP + c * DP + d] = f2bf(w - bf2f(hi));
    }
}

// ---------------------------------------------------------------------------
// Kernel 0b: mask -> bitmask. One wave per (b, n1) row; 32 ballot iterations
// compress 2048 int32 to 64 u32 words. Fully coalesced 256B/instr reads.
// ---------------------------------------------------------------------------
__global__ __launch_bounds__(256)
void maskprep(const int* __restrict__ mask, u32* __restrict__ bits){
    int wid  = (blockIdx.x * 256 + threadIdx.x) >> 6;   // global wave id = row
    int lane = threadIdx.x & 63;
    long base = (long)wid * N_;
    u32 myw = 0;
    #pragma unroll
    for (int it = 0; it < 32; ++it){
        int v = mask[base + it * 64 + lane];
        unsigned long long bb = __ballot(v != 0);
        if ((lane >> 1) == it)
            myw = (lane & 1) ? (u32)(bb >> 32) : (u32)bb;
    }
    bits[((long)wid << 6) + lane] = myw;
}

// ---------------------------------------------------------------------------
// Kernel 1: projections via 3-term split-bf16 MFMA.
// ---------------------------------------------------------------------------
__global__ __launch_bounds__(256, 4)
void proj_kernel(const float* __restrict__ x1, const float* __restrict__ x2,
                 const u16* __restrict__ Wth, const u16* __restrict__ Wtl,
                 u16* __restrict__ Qh, u16* __restrict__ Ql,
                 u16* __restrict__ Kh, u16* __restrict__ Kl,
                 u16* __restrict__ Vt){
    int p    = blockIdx.y;
    const float* x = (p == 0) ? x1 : x2;
    int wave = threadIdx.x >> 6, lane = threadIdx.x & 63;
    int g = lane >> 4, ln = lane & 15;
    long arow = (long)blockIdx.x * 64 + wave * 16 + ln;     // A row (M index)

    // A fragments: lane holds row (lane&15), k = 8*(lane>>4)+j
    short8 ah[4], al[4];
    #pragma unroll
    for (int ks = 0; ks < 4; ++ks){
        int d0 = ks * 32 + g * 8;
        float xv[8];
        if (d0 < D_){
            float4v v0 = *(const float4v*)(x + arow * D_ + d0);
            float4v v1 = *(const float4v*)(x + arow * D_ + d0 + 4);
            xv[0]=v0[0]; xv[1]=v0[1]; xv[2]=v0[2]; xv[3]=v0[3];
            xv[4]=v1[0]; xv[5]=v1[1]; xv[6]=v1[2]; xv[7]=v1[3];
        } else {
            #pragma unroll
            for (int j = 0; j < 8; ++j) xv[j] = 0.f;
        }
        short8 h, l;
        #pragma unroll
        for (int j = 0; j < 8; ++j){
            u16 hb = f2bf(xv[j]);
            h[j] = (short)hb;
            l[j] = (short)f2bf(xv[j] - bf2f(hb));
        }
        ah[ks] = h; al[ks] = l;
    }

    const u16* wh = Wth + p * DP * DP;
    const u16* wl = Wtl + p * DP * DP;
    f32x4 acc[8];
    #pragma unroll
    for (int cf = 0; cf < 8; ++cf){
        f32x4 a = {0.f, 0.f, 0.f, 0.f};
        #pragma unroll
        for (int ks = 0; ks < 4; ++ks){
            short8 bh = *(const short8*)(wh + (cf * 16 + ln) * DP + ks * 32 + g * 8);
            short8 bl = *(const short8*)(wl + (cf * 16 + ln) * DP + ks * 32 + g * 8);
            a = mfma16(ah[ks], bh, a);
            a = mfma16(ah[ks], bl, a);
            a = mfma16(al[ks], bh, a);
        }
        acc[cf] = a;
    }

    // C/D layout: col = lane&15, row = 4*(lane>>4)+i
    #pragma unroll
    for (int cf = 0; cf < 8; ++cf){
        #pragma unroll
        for (int i = 0; i < 4; ++i){
            long orow = (long)blockIdx.x * 64 + wave * 16 + g * 4 + i;
            int  c    = cf * 16 + ln;
            float v   = acc[cf][i];
            if (p == 0){
                u16 hb = f2bf(v);
                Qh[orow * DP + c] = hb;
                Ql[orow * DP + c] = f2bf(v - bf2f(hb));
            } else if (p == 1){
                u16 hb = f2bf(v);
                Kh[orow * DP + c] = hb;
                Kl[orow * DP + c] = f2bf(v - bf2f(hb));
            } else {
                long bb = orow >> 11, n = orow & 2047;
                Vt[(bb * DP + c) * N_ + n] = f2bf(v);
            }
        }
    }
}

// ---------------------------------------------------------------------------
// Kernel 2: fused scores + softmax + attn-weight store + PV.
// Grid (128, 8): block = (batch, 16 q-rows). 8 waves; wave w owns the 16x256
// column slice [w*256, w*256+256). Scores: sc[16] f32x4 = 64 VGPR.
// P-transpose via wave-private LDS tile (no barrier); attnw stored dwordx4;
// PV fed from registers (pa[8]); cross-wave output reduce via LDS atomics.
// ---------------------------------------------------------------------------
__global__ __launch_bounds__(512, 4)
void attn_kernel(const u16* __restrict__ Qh, const u16* __restrict__ Ql,
                 const u16* __restrict__ Kh, const u16* __restrict__ Kl,
                 const u16* __restrict__ Vt, const u32* __restrict__ bits,
                 float* __restrict__ outp, float* __restrict__ attnw){
    __shared__ float tile[8][16 * 34];   // per-wave transpose tiles (17408 B)
    __shared__ float red0[8][16];        // row-max partials
    __shared__ float red1[8][16];        // row-sum partials
    __shared__ float outred[16 * 128];   // 8 KB output reduce

    int b  = blockIdx.y;
    int q0 = blockIdx.x * QB;
    int w  = threadIdx.x >> 6, lane = threadIdx.x & 63;
    int g  = lane >> 4, ln = lane & 15;
    long rowbase = (long)b * N_ + q0;

    // zero output-reduce buffer early (softmax syncs cover visibility)
    #pragma unroll
    for (int idx = threadIdx.x; idx < 16 * 128; idx += 512) outred[idx] = 0.f;

    // ---- Q A-fragments ----
    short8 ah[4], al[4];
    #pragma unroll
    for (int ks = 0; ks < 4; ++ks){
        ah[ks] = *(const short8*)(Qh + (rowbase + ln) * DP + ks * 32 + g * 8);
        al[ks] = *(const short8*)(Ql + (rowbase + ln) * DP + ks * 32 + g * 8);
    }

    // ---- scores: S = Qs @ K^T (3-term split) ----
    f32x4 sc[16];
    #pragma unroll
    for (int cf = 0; cf < 16; ++cf){
        long krow = (long)b * N_ + w * 256 + cf * 16 + ln;
        const u16* kh = Kh + krow * DP;
        const u16* kl = Kl + krow * DP;
        f32x4 a = {0.f, 0.f, 0.f, 0.f};
        #pragma unroll
        for (int ks = 0; ks < 4; ++ks){
            short8 bh = *(const short8*)(kh + ks * 32 + g * 8);
            short8 bl = *(const short8*)(kl + ks * 32 + g * 8);
            a = mfma16(ah[ks], bh, a);
            a = mfma16(ah[ks], bl, a);
            a = mfma16(al[ks], bh, a);
        }
        sc[cf] = a;
    }

    // ---- mask via bitmask (4 MB, L2/L3-resident) ----
    const u32* bb = bits + rowbase * 64 + w * 8;
    #pragma unroll
    for (int i = 0; i < 4; ++i){
        const u32* rp = bb + (long)(g * 4 + i) * 64;
        u32x4 m0 = *(const u32x4*)rp;
        u32x4 m1 = *(const u32x4*)(rp + 4);
        u32 mw[8] = {m0[0], m0[1], m0[2], m0[3], m1[0], m1[1], m1[2], m1[3]};
        #pragma unroll
        for (int cf = 0; cf < 16; ++cf){
            u32 word = mw[cf >> 1];
            int bit  = (cf & 1) * 16 + ln;
            if (!((word >> bit) & 1u)) sc[cf][i] = -__builtin_inff();
        }
    }

    // ---- row max: in-wave over 16 cols x 16 frags, then cross-wave ----
    float mx[4];
    #pragma unroll
    for (int i = 0; i < 4; ++i){
        float m = sc[0][i];
        #pragma unroll
        for (int cf = 1; cf < 16; ++cf) m = fmaxf(m, sc[cf][i]);
        #pragma unroll
        for (int s = 1; s < 16; s <<= 1) m = fmaxf(m, __shfl_xor(m, s, 64));
        mx[i] = m;
    }
    if (ln == 0){
        #pragma unroll
        for (int i = 0; i < 4; ++i) red0[w][g * 4 + i] = mx[i];
    }
    __syncthreads();
    float fm[4];
    #pragma unroll
    for (int i = 0; i < 4; ++i){
        int r = g * 4 + i;
        float m = red0[0][r];
        #pragma unroll
        for (int w2 = 1; w2 < 8; ++w2) m = fmaxf(m, red0[w2][r]);
        fm[i] = m;
    }

    // ---- exp + row sum ----
    float sm[4] = {0.f, 0.f, 0.f, 0.f};
    #pragma unroll
    for (int cf = 0; cf < 16; ++cf){
        #pragma unroll
        for (int i = 0; i < 4; ++i){
            float e = __expf(sc[cf][i] - fm[i]);
            sc[cf][i] = e;
            sm[i] += e;
        }
    }
    #pragma unroll
    for (int i = 0; i < 4; ++i){
        float s = sm[i];
        #pragma unroll
        for (int sft = 1; sft < 16; sft <<= 1) s += __shfl_xor(s, sft, 64);
        sm[i] = s;
    }
    if (ln == 0){
        #pragma unroll
        for (int i = 0; i < 4; ++i) red1[w][g * 4 + i] = sm[i];
    }
    __syncthreads();
    float inv[4];
    #pragma unroll
    for (int i = 0; i < 4; ++i){
        int r = g * 4 + i;
        float s = red1[0][r];
        #pragma unroll
        for (int w2 = 1; w2 < 8; ++w2) s += red1[w2][r];
        inv[i] = 1.f / s;
    }

    // ---- per-32-col chunks: LDS transpose -> vectorized attnw store + pa ----
    float* mytile = &tile[w][0];
    short8 pa[8];
    #pragma unroll
    for (int mc = 0; mc < 8; ++mc){
        // write C-layout (normalized) into wave-private tile [16][34]
        #pragma unroll
        for (int t = 0; t < 2; ++t){
            #pragma unroll
            for (int i = 0; i < 4; ++i)
                mytile[(g * 4 + i) * 34 + t * 16 + ln] = sc[mc * 2 + t][i] * inv[i];
        }
        // read A-layout: row ln, 8 consecutive cols at g*8 (b64 reads)
        float p[8];
        #pragma unroll
        for (int k = 0; k < 4; ++k){
            f32x2 t2 = *(const f32x2*)&mytile[ln * 34 + g * 8 + 2 * k];
            p[2 * k] = t2[0]; p[2 * k + 1] = t2[1];
        }
        // vectorized attnw store (16B x2 per lane)
        float* ap = attnw + (rowbase + ln) * N_ + w * 256 + mc * 32 + g * 8;
        f32x4 s0 = {p[0], p[1], p[2], p[3]};
        f32x4 s1 = {p[4], p[5], p[6], p[7]};
        *(f32x4*)ap       = s0;
        *(f32x4*)(ap + 4) = s1;
        // A-fragment for PV
        short8 t8;
        #pragma unroll
        for (int j = 0; j < 8; ++j) t8[j] = (short)f2bf(p[j]);
        pa[mc] = t8;
    }

    // ---- PV: out += P @ V ----
    f32x4 oacc[8];
    #pragma unroll
    for (int e = 0; e < 8; ++e) oacc[e] = (f32x4){0.f, 0.f, 0.f, 0.f};
    #pragma unroll
    for (int mc = 0; mc < 8; ++mc){
        const u16* vbase = Vt + ((long)b * DP + ln) * N_ + w * 256 + mc * 32 + g * 8;
        #pragma unroll
        for (int e = 0; e < 8; ++e){
            short8 vb = *(const short8*)(vbase + (long)e * 16 * N_);
            oacc[e] = mfma16(pa[mc], vb, oacc[e]);
        }
    }

    // ---- cross-wave reduce (LDS float atomics) + store output ----
    __syncthreads();   // ensure all zeroing visible & phases aligned
    #pragma unroll
    for (int e = 0; e < 8; ++e){
        #pragma unroll
        for (int i = 0; i < 4; ++i)
            atomicAdd(&outred[(g * 4 + i) * 128 + e * 16 + ln], oacc[e][i]);
    }
    __syncthreads();
    {
        int t4  = threadIdx.x * 4;
        int row = t4 >> 7;
        int e0  = t4 & 127;
        if (e0 <= 116){
            f32x4 v = {outred[row * 128 + e0],     outred[row * 128 + e0 + 1],
                       outred[row * 128 + e0 + 2], outred[row * 128 + e0 + 3]};
            *(f32x4*)(outp + (rowbase + row) * D_ + e0) = v;
        }
    }
}

// ---------------------------------------------------------------------------
extern "C" void kernel_launch(void* const* d_in, const int* in_sizes, int n_in,
                              void* d_out, int out_size, void* d_ws, size_t ws_size,
                              hipStream_t stream){
    const float* x1   = (const float*)d_in[0];
    const float* x2   = (const float*)d_in[1];
    const int*   mask = (const int*)d_in[2];
    const float* Wq   = (const float*)d_in[3];
    const float* Wk   = (const float*)d_in[4];
    const float* Wv   = (const float*)d_in[5];

    float* outp  = (float*)d_out;
    float* attnw = outp + (size_t)B_ * N_ * D_;   // outputs concatenated flat

    // workspace carve: bits (4MB) + 5 x 4MB bf16 tensors + split weights
    const size_t TEN = (size_t)B_ * N_ * DP;      // 2,097,152
    u32* bits = (u32*)d_ws;                       // B*N*64 u32 = 4 MB
    u16* Qh   = (u16*)(bits + (size_t)B_ * N_ * 64);
    u16* Ql   = Qh + TEN;
    u16* Kh   = Ql + TEN;
    u16* Kl   = Kh + TEN;
    u16* Vt   = Kl + TEN;                         // [B][DP][N] transposed V
    u16* Wth  = Vt + TEN;
    u16* Wtl  = Wth + (size_t)3 * DP * DP;

    hipLaunchKernelGGL(wprep, dim3(3), dim3(256), 0, stream, Wq, Wk, Wv, Wth, Wtl);
    hipLaunchKernelGGL(maskprep, dim3((B_ * N_) / 4), dim3(256), 0, stream, mask, bits);
    hipLaunchKernelGGL(proj_kernel, dim3((B_ * N_) / 64, 3), dim3(256), 0, stream,
                       x1, x2, Wth, Wtl, Qh, Ql, Kh, Kl, Vt);
    hipLaunchKernelGGL(attn_kernel, dim3(N_ / QB, B_), dim3(512), 0, stream,
                       Qh, Ql, Kh, Kl, Vt, bits, outp, attnw);
}

// Round 6
// 252.521 us; speedup vs baseline: 1.5398x; 1.5398x over previous
//
#include <hip/hip_runtime.h>
#include <stdint.h>

#define B_ 8
#define N_ 2048
#define D_ 120
#define DP 128          // D padded to 128 (k-dim of MFMA)
#define QBLK 64         // q rows per attention block
#define MT 32           // m-tile (k/v rows per step)
#define NT (N_ / MT)    // 64 steps

typedef __attribute__((ext_vector_type(8))) short short8;
typedef __attribute__((ext_vector_type(4))) float f32x4;
typedef __attribute__((ext_vector_type(4))) float float4v;
typedef unsigned short u16;
typedef unsigned int u32;

// f32 -> bf16 (RNE) and back, bit-level (all values finite here)
__device__ __forceinline__ u16 f2bf(float f){
    union { float f; uint32_t u; } v; v.f = f;
    uint32_t u = v.u;
    return (u16)((u + 0x7fffu + ((u >> 16) & 1u)) >> 16);
}
__device__ __forceinline__ float bf2f(u16 h){
    union { uint32_t u; float f; } v; v.u = ((uint32_t)h) << 16; return v.f;
}

__device__ __forceinline__ f32x4 mfma16(short8 a, short8 b, f32x4 c){
    return __builtin_amdgcn_mfma_f32_16x16x32_bf16(a, b, c, 0, 0, 0);
}

// ---------------------------------------------------------------------------
// Kernel 0: transpose + split weights. Wt[c][d] (bf16 hi/lo), zero-padded to
// 128x128. Scale 1/sqrt(D) folded into W_query.
// ---------------------------------------------------------------------------
__global__ void wprep(const float* __restrict__ Wq, const float* __restrict__ Wk,
                      const float* __restrict__ Wv,
                      u16* __restrict__ Wth, u16* __restrict__ Wtl){
    int p = blockIdx.x;
    const float* W = (p == 0) ? Wq : (p == 1 ? Wk : Wv);
    float scale = (p == 0) ? 0.09128709291752768f : 1.0f;  // 1/sqrt(120)
    for (int idx = threadIdx.x; idx < DP * DP; idx += blockDim.x){
        int c = idx & (DP - 1);
        int d = idx >> 7;
        float w = (c < D_ && d < D_) ? W[d * D_ + c] * scale : 0.f;
        u16 hi = f2bf(w);
        Wth[p * DP * DP + c * DP + d] = hi;
        Wtl[p * DP * DP + c * DP + d] = f2bf(w - bf2f(hi));
    }
}

// ---------------------------------------------------------------------------
// Kernel 0b: mask -> bitmask (2048 int32 -> 64 u32 per row), coalesced.
// ---------------------------------------------------------------------------
__global__ __launch_bounds__(256)
void maskprep(const int* __restrict__ mask, u32* __restrict__ bits){
    int wid  = (blockIdx.x * 256 + threadIdx.x) >> 6;   // global wave id = row
    int lane = threadIdx.x & 63;
    long base = (long)wid * N_;
    u32 myw = 0;
    #pragma unroll
    for (int it = 0; it < 32; ++it){
        int v = mask[base + it * 64 + lane];
        unsigned long long bb = __ballot(v != 0);
        if ((lane >> 1) == it)
            myw = (lane & 1) ? (u32)(bb >> 32) : (u32)bb;
    }
    bits[((long)wid << 6) + lane] = myw;
}

// ---------------------------------------------------------------------------
// Kernel 1: projections via 3-term split-bf16 MFMA (unchanged).
// ---------------------------------------------------------------------------
__global__ __launch_bounds__(256, 4)
void proj_kernel(const float* __restrict__ x1, const float* __restrict__ x2,
                 const u16* __restrict__ Wth, const u16* __restrict__ Wtl,
                 u16* __restrict__ Qh, u16* __restrict__ Ql,
                 u16* __restrict__ Kh, u16* __restrict__ Kl,
                 u16* __restrict__ Vt){
    int p    = blockIdx.y;
    const float* x = (p == 0) ? x1 : x2;
    int wave = threadIdx.x >> 6, lane = threadIdx.x & 63;
    int g = lane >> 4, ln = lane & 15;
    long arow = (long)blockIdx.x * 64 + wave * 16 + ln;     // A row (M index)

    short8 ah[4], al[4];
    #pragma unroll
    for (int ks = 0; ks < 4; ++ks){
        int d0 = ks * 32 + g * 8;
        float xv[8];
        if (d0 < D_){
            float4v v0 = *(const float4v*)(x + arow * D_ + d0);
            float4v v1 = *(const float4v*)(x + arow * D_ + d0 + 4);
            xv[0]=v0[0]; xv[1]=v0[1]; xv[2]=v0[2]; xv[3]=v0[3];
            xv[4]=v1[0]; xv[5]=v1[1]; xv[6]=v1[2]; xv[7]=v1[3];
        } else {
            #pragma unroll
            for (int j = 0; j < 8; ++j) xv[j] = 0.f;
        }
        short8 h, l;
        #pragma unroll
        for (int j = 0; j < 8; ++j){
            u16 hb = f2bf(xv[j]);
            h[j] = (short)hb;
            l[j] = (short)f2bf(xv[j] - bf2f(hb));
        }
        ah[ks] = h; al[ks] = l;
    }

    const u16* wh = Wth + p * DP * DP;
    const u16* wl = Wtl + p * DP * DP;
    f32x4 acc[8];
    #pragma unroll
    for (int cf = 0; cf < 8; ++cf){
        f32x4 a = {0.f, 0.f, 0.f, 0.f};
        #pragma unroll
        for (int ks = 0; ks < 4; ++ks){
            short8 bh = *(const short8*)(wh + (cf * 16 + ln) * DP + ks * 32 + g * 8);
            short8 bl = *(const short8*)(wl + (cf * 16 + ln) * DP + ks * 32 + g * 8);
            a = mfma16(ah[ks], bh, a);
            a = mfma16(ah[ks], bl, a);
            a = mfma16(al[ks], bh, a);
        }
        acc[cf] = a;
    }

    #pragma unroll
    for (int cf = 0; cf < 8; ++cf){
        #pragma unroll
        for (int i = 0; i < 4; ++i){
            long orow = (long)blockIdx.x * 64 + wave * 16 + g * 4 + i;
            int  c    = cf * 16 + ln;
            float v   = acc[cf][i];
            if (p == 0){
                u16 hb = f2bf(v);
                Qh[orow * DP + c] = hb;
                Ql[orow * DP + c] = f2bf(v - bf2f(hb));
            } else if (p == 1){
                u16 hb = f2bf(v);
                Kh[orow * DP + c] = hb;
                Kl[orow * DP + c] = f2bf(v - bf2f(hb));
            } else {
                long bb = orow >> 11, n = orow & 2047;
                Vt[(bb * DP + c) * N_ + n] = f2bf(v);
            }
        }
    }
}

// ---------------------------------------------------------------------------
// Kernel 2: flash-style fused attention. Block = 64 q-rows, 8 waves
// (rt in 0..3 row-tile, wc in 0..1 m/e-half). m-loop over 64 tiles of 32.
// K staged coalesced -> XOR-swizzled LDS; V reg-staged -> swizzled LDS;
// double-buffered. Pass A: online (max, l). Pass B: recompute S, normalize,
// coalesced attnw store via LDS P-tile, PV from LDS fragments.
// ---------------------------------------------------------------------------
__global__ __launch_bounds__(512, 2)
void attn_kernel(const u16* __restrict__ Qh, const u16* __restrict__ Ql,
                 const u16* __restrict__ Kh, const u16* __restrict__ Kl,
                 const u16* __restrict__ Vt, const u32* __restrict__ bits,
                 float* __restrict__ outp, float* __restrict__ attnw){
    __shared__ short8 KsH[2][512];     // [buf][32 m-rows x 16 units] swizzled
    __shared__ short8 KsL[2][512];
    __shared__ short8 Vs [2][512];     // [buf][128 e-rows x 4 units] swizzled
    __shared__ float  Ps[QBLK * 32];   // P tile, col ^ ((row&7)<<2) swizzle
    __shared__ float  redM[2][QBLK];
    __shared__ float  redL[2][QBLK];
    __shared__ float  smax[QBLK];
    __shared__ float  sinv[QBLK];

    int lin = blockIdx.x;
    int b   = lin & 7;                  // same-batch blocks land on one XCD
    int q0  = (lin >> 3) * QBLK;
    int tid = threadIdx.x;
    int w   = tid >> 6, lane = tid & 63;
    int rt  = w >> 1, wc = w & 1;
    int g   = lane >> 4, ln = lane & 15;

    long rowbase = (long)b * N_ + q0;
    long kbase   = (long)b * N_ * DP;   // u16 offset into Kh/Kl
    long vbase   = (long)b * DP * N_;   // u16 offset into Vt

    // ---- Q A-fragments (rows rt*16+ln) ----
    short8 ah[4], al[4];
    {
        const u16* qh = Qh + (rowbase + rt * 16 + ln) * DP;
        const u16* ql = Ql + (rowbase + rt * 16 + ln) * DP;
        #pragma unroll
        for (int ks = 0; ks < 4; ++ks){
            ah[ks] = *(const short8*)(qh + ks * 32 + g * 8);
            al[ks] = *(const short8*)(ql + ks * 32 + g * 8);
        }
    }

    int mrow  = wc * 16 + ln;                 // m-local row this wave reads
    int swzK  = ln & 7;                       // K-read column XOR
    long bitrow[4];
    #pragma unroll
    for (int i = 0; i < 4; ++i) bitrow[i] = (rowbase + rt * 16 + g * 4 + i) * 64;
    int mybit = wc * 16 + ln;

    // ================= PASS A: online max / sum =================
    float mx[4], ls[4];
    #pragma unroll
    for (int i = 0; i < 4; ++i){ mx[i] = -1e30f; ls[i] = 0.f; }

    {   // prologue: stage K tile 0
        long gb = kbase + (long)tid * 8;
        short8 h  = *(const short8*)(Kh + gb);
        short8 l8 = *(const short8*)(Kl + gb);
        int row = tid >> 4, cu = tid & 15;
        int d = row * 16 + (cu ^ (row & 7));
        KsH[0][d] = h; KsL[0][d] = l8;
        __syncthreads();
    }
    for (int t = 0; t < NT; ++t){
        int cb = t & 1, nb = cb ^ 1;
        short8 khr, klr;
        if (t + 1 < NT){
            long gb = kbase + (long)(t + 1) * MT * DP + (long)tid * 8;
            khr = *(const short8*)(Kh + gb);
            klr = *(const short8*)(Kl + gb);
        }
        // S fragment (16 q x 16 m), 3-term split
        f32x4 s = {0.f, 0.f, 0.f, 0.f};
        #pragma unroll
        for (int ks = 0; ks < 4; ++ks){
            int cu = (ks * 4 + g) ^ swzK;
            short8 bh = KsH[cb][mrow * 16 + cu];
            short8 bl = KsL[cb][mrow * 16 + cu];
            s = mfma16(ah[ks], bh, s);
            s = mfma16(ah[ks], bl, s);
            s = mfma16(al[ks], bh, s);
        }
        // mask + per-lane online update
        #pragma unroll
        for (int i = 0; i < 4; ++i){
            u32 word = bits[bitrow[i] + t];
            if ((word >> mybit) & 1u){
                float sv = s[i];
                float nm = fmaxf(mx[i], sv);
                ls[i] = ls[i] * __expf(mx[i] - nm) + __expf(sv - nm);
                mx[i] = nm;
            }
        }
        if (t + 1 < NT){
            int row = tid >> 4, cu = tid & 15;
            int d = row * 16 + (cu ^ (row & 7));
            KsH[nb][d] = khr; KsL[nb][d] = klr;
        }
        __syncthreads();
    }

    // lane-reduce over the 16 ln lanes (rows preserved: xor stays in g-group)
    #pragma unroll
    for (int i = 0; i < 4; ++i){
        #pragma unroll
        for (int sft = 1; sft < 16; sft <<= 1){
            float om = __shfl_xor(mx[i], sft, 64);
            float ol = __shfl_xor(ls[i], sft, 64);
            float nm = fmaxf(mx[i], om);
            ls[i] = ls[i] * __expf(mx[i] - nm) + ol * __expf(om - nm);
            mx[i] = nm;
        }
    }
    if (ln == 0){
        #pragma unroll
        for (int i = 0; i < 4; ++i){
            redM[wc][rt * 16 + g * 4 + i] = mx[i];
            redL[wc][rt * 16 + g * 4 + i] = ls[i];
        }
    }
    __syncthreads();
    if (tid < QBLK){
        float m0 = redM[0][tid], m1 = redM[1][tid];
        float M  = fmaxf(m0, m1);
        float L  = redL[0][tid] * __expf(m0 - M) + redL[1][tid] * __expf(m1 - M);
        smax[tid] = M;
        sinv[tid] = 1.f / L;
    }
    __syncthreads();
    float Mr[4], Ir[4];
    #pragma unroll
    for (int i = 0; i < 4; ++i){
        Mr[i] = smax[rt * 16 + g * 4 + i];
        Ir[i] = sinv[rt * 16 + g * 4 + i];
    }

    // ================= PASS B: P store + PV =================
    f32x4 acc[4];
    #pragma unroll
    for (int e = 0; e < 4; ++e) acc[e] = (f32x4){0.f, 0.f, 0.f, 0.f};

    {   // prologue: stage K+V tile 0
        long gb = kbase + (long)tid * 8;
        short8 h  = *(const short8*)(Kh + gb);
        short8 l8 = *(const short8*)(Kl + gb);
        short8 v  = *(const short8*)(Vt + vbase + (long)(tid >> 2) * N_ + (tid & 3) * 8);
        int row = tid >> 4, cu = tid & 15;
        KsH[0][row * 16 + (cu ^ (row & 7))] = h;
        KsL[0][row * 16 + (cu ^ (row & 7))] = l8;
        int e = tid >> 2, mu = tid & 3;
        Vs[0][e * 4 + (mu ^ ((e >> 1) & 3))] = v;
        __syncthreads();
    }
    for (int t = 0; t < NT; ++t){
        int cb = t & 1, nb = cb ^ 1;
        short8 khr, klr, vr;
        if (t + 1 < NT){
            long gb = kbase + (long)(t + 1) * MT * DP + (long)tid * 8;
            khr = *(const short8*)(Kh + gb);
            klr = *(const short8*)(Kl + gb);
            vr  = *(const short8*)(Vt + vbase + (long)(tid >> 2) * N_ + (t + 1) * MT + (tid & 3) * 8);
        }
        // S recompute
        f32x4 s = {0.f, 0.f, 0.f, 0.f};
        #pragma unroll
        for (int ks = 0; ks < 4; ++ks){
            int cu = (ks * 4 + g) ^ swzK;
            short8 bh = KsH[cb][mrow * 16 + cu];
            short8 bl = KsL[cb][mrow * 16 + cu];
            s = mfma16(ah[ks], bh, s);
            s = mfma16(ah[ks], bl, s);
            s = mfma16(al[ks], bh, s);
        }
        // normalized P -> swizzled LDS tile
        #pragma unroll
        for (int i = 0; i < 4; ++i){
            u32 word = bits[bitrow[i] + t];
            float p = ((word >> mybit) & 1u) ? __expf(s[i] - Mr[i]) * Ir[i] : 0.f;
            int prow = rt * 16 + g * 4 + i;
            Ps[prow * 32 + (mybit ^ ((prow & 7) << 2))] = p;
        }
        __syncthreads();   // P tile ready; all K[cb] reads done

        // coalesced attnw store: 8 rows x 128B per wave-instr
        {
            int row = tid >> 3, cg = tid & 7;
            f32x4 pv = *(const f32x4*)&Ps[row * 32 + ((cg * 4) ^ ((row & 7) << 2))];
            *(f32x4*)(attnw + (rowbase + row) * N_ + t * MT + cg * 4) = pv;
        }
        // PV: A-fragment from P tile, B-fragments from swizzled Vs
        short8 pa;
        {
            int prow = rt * 16 + ln;
            int sx = (prow & 7) << 2;
            f32x4 p0 = *(const f32x4*)&Ps[prow * 32 + ((g * 8)     ^ sx)];
            f32x4 p1 = *(const f32x4*)&Ps[prow * 32 + ((g * 8 + 4) ^ sx)];
            #pragma unroll
            for (int j = 0; j < 4; ++j){
                pa[j]     = (short)f2bf(p0[j]);
                pa[4 + j] = (short)f2bf(p1[j]);
            }
        }
        #pragma unroll
        for (int ef = 0; ef < 4; ++ef){
            int e = wc * 64 + ef * 16 + ln;
            short8 vb = Vs[cb][e * 4 + (g ^ ((e >> 1) & 3))];
            acc[ef] = mfma16(pa, vb, acc[ef]);
        }
        if (t + 1 < NT){
            int row = tid >> 4, cu = tid & 15;
            KsH[nb][row * 16 + (cu ^ (row & 7))] = khr;
            KsL[nb][row * 16 + (cu ^ (row & 7))] = klr;
            int e = tid >> 2, mu = tid & 3;
            Vs[nb][e * 4 + (mu ^ ((e >> 1) & 3))] = vr;
        }
        __syncthreads();
    }

    // ---- output store ----
    #pragma unroll
    for (int ef = 0; ef < 4; ++ef){
        #pragma unroll
        for (int i = 0; i < 4; ++i){
            int col = wc * 64 + ef * 16 + ln;
            if (col < D_)
                outp[(rowbase + rt * 16 + g * 4 + i) * D_ + col] = acc[ef][i];
        }
    }
}

// ---------------------------------------------------------------------------
extern "C" void kernel_launch(void* const* d_in, const int* in_sizes, int n_in,
                              void* d_out, int out_size, void* d_ws, size_t ws_size,
                              hipStream_t stream){
    const float* x1   = (const float*)d_in[0];
    const float* x2   = (const float*)d_in[1];
    const int*   mask = (const int*)d_in[2];
    const float* Wq   = (const float*)d_in[3];
    const float* Wk   = (const float*)d_in[4];
    const float* Wv   = (const float*)d_in[5];

    float* outp  = (float*)d_out;
    float* attnw = outp + (size_t)B_ * N_ * D_;   // outputs concatenated flat

    const size_t TEN = (size_t)B_ * N_ * DP;      // 2,097,152
    u32* bits = (u32*)d_ws;                       // B*N*64 u32 = 4 MB
    u16* Qh   = (u16*)(bits + (size_t)B_ * N_ * 64);
    u16* Ql   = Qh + TEN;
    u16* Kh   = Ql + TEN;
    u16* Kl   = Kh + TEN;
    u16* Vt   = Kl + TEN;                         // [B][DP][N] transposed V
    u16* Wth  = Vt + TEN;
    u16* Wtl  = Wth + (size_t)3 * DP * DP;

    hipLaunchKernelGGL(wprep, dim3(3), dim3(256), 0, stream, Wq, Wk, Wv, Wth, Wtl);
    hipLaunchKernelGGL(maskprep, dim3((B_ * N_) / 4), dim3(256), 0, stream, mask, bits);
    hipLaunchKernelGGL(proj_kernel, dim3((B_ * N_) / 64, 3), dim3(256), 0, stream,
                       x1, x2, Wth, Wtl, Qh, Ql, Kh, Kl, Vt);
    hipLaunchKernelGGL(attn_kernel, dim3((B_ * N_) / QBLK), dim3(512), 0, stream,
                       Qh, Ql, Kh, Kl, Vt, bits, outp, attnw);
}

// Round 7
// 223.640 us; speedup vs baseline: 1.7387x; 1.1291x over previous
//
#include <hip/hip_runtime.h>
#include <stdint.h>

#define B_ 8
#define N_ 2048
#define D_ 120
#define DP 128          // D padded to 128 (k-dim of MFMA)
#define QB 32           // q rows per attention block
#define MT 32           // m-tile (k/v rows per step)
#define NT (N_ / MT)    // 64 steps

typedef __attribute__((ext_vector_type(8))) short short8;
typedef __attribute__((ext_vector_type(4))) float f32x4;
typedef __attribute__((ext_vector_type(4))) float float4v;
typedef unsigned short u16;
typedef unsigned int u32;

__device__ __forceinline__ u16 f2bf(float f){
    union { float f; uint32_t u; } v; v.f = f;
    uint32_t u = v.u;
    return (u16)((u + 0x7fffu + ((u >> 16) & 1u)) >> 16);
}
__device__ __forceinline__ float bf2f(u16 h){
    union { uint32_t u; float f; } v; v.u = ((uint32_t)h) << 16; return v.f;
}
__device__ __forceinline__ f32x4 mfma16(short8 a, short8 b, f32x4 c){
    return __builtin_amdgcn_mfma_f32_16x16x32_bf16(a, b, c, 0, 0, 0);
}

// ---------------------------------------------------------------------------
// Kernel 0: transpose + split weights (bf16 hi/lo), zero-padded to 128x128.
// ---------------------------------------------------------------------------
__global__ void wprep(const float* __restrict__ Wq, const float* __restrict__ Wk,
                      const float* __restrict__ Wv,
                      u16* __restrict__ Wth, u16* __restrict__ Wtl){
    int p = blockIdx.x;
    const float* W = (p == 0) ? Wq : (p == 1 ? Wk : Wv);
    float scale = (p == 0) ? 0.09128709291752768f : 1.0f;  // 1/sqrt(120)
    for (int idx = threadIdx.x; idx < DP * DP; idx += blockDim.x){
        int c = idx & (DP - 1);
        int d = idx >> 7;
        float w = (c < D_ && d < D_) ? W[d * D_ + c] * scale : 0.f;
        u16 hi = f2bf(w);
        Wth[p * DP * DP + c * DP + d] = hi;
        Wtl[p * DP * DP + c * DP + d] = f2bf(w - bf2f(hi));
    }
}

// ---------------------------------------------------------------------------
// Kernel 0b: mask -> bitmask (2048 int32 -> 64 u32 per row), coalesced.
// ---------------------------------------------------------------------------
__global__ __launch_bounds__(256)
void maskprep(const int* __restrict__ mask, u32* __restrict__ bits){
    int wid  = (blockIdx.x * 256 + threadIdx.x) >> 6;
    int lane = threadIdx.x & 63;
    long base = (long)wid * N_;
    u32 myw = 0;
    #pragma unroll
    for (int it = 0; it < 32; ++it){
        int v = mask[base + it * 64 + lane];
        unsigned long long bb = __ballot(v != 0);
        if ((lane >> 1) == it)
            myw = (lane & 1) ? (u32)(bb >> 32) : (u32)bb;
    }
    bits[((long)wid << 6) + lane] = myw;
}

// ---------------------------------------------------------------------------
// Kernel 1: projections. W (hi+lo) staged in swizzled LDS; V written
// tile-major [b][t][e][32] via LDS transpose (coalesced stores).
// ---------------------------------------------------------------------------
__global__ __launch_bounds__(256, 2)
void proj_kernel(const float* __restrict__ x1, const float* __restrict__ x2,
                 const u16* __restrict__ Wth, const u16* __restrict__ Wtl,
                 u16* __restrict__ Qh, u16* __restrict__ Ql,
                 u16* __restrict__ Kh, u16* __restrict__ Kl,
                 u16* __restrict__ Vt){
    __shared__ short8 smem8[4096];          // 64 KB: WH[2048] | WL[2048]
    short8* WHs = smem8;
    short8* WLs = smem8 + 2048;
    u16* vtl = (u16*)smem8;                 // reused after compute: [128][64]

    int p    = blockIdx.y;
    const float* x = (p == 0) ? x1 : x2;
    int tid  = threadIdx.x;
    int wave = tid >> 6, lane = tid & 63;
    int g = lane >> 4, ln = lane & 15;
    long arow = (long)blockIdx.x * 64 + wave * 16 + ln;

    // stage W hi/lo into swizzled LDS
    const u16* wh = Wth + p * DP * DP;
    const u16* wl = Wtl + p * DP * DP;
    #pragma unroll
    for (int j = 0; j < 8; ++j){
        int u = tid + j * 256;
        int row = u >> 4, cu = u & 15;
        int slot = row * 16 + (cu ^ (row & 7));
        WHs[slot] = *(const short8*)(wh + (long)u * 8);
        WLs[slot] = *(const short8*)(wl + (long)u * 8);
    }

    // A fragments from x
    short8 ah[4], al[4];
    #pragma unroll
    for (int ks = 0; ks < 4; ++ks){
        int d0 = ks * 32 + g * 8;
        float xv[8];
        if (d0 < D_){
            float4v v0 = *(const float4v*)(x + arow * D_ + d0);
            float4v v1 = *(const float4v*)(x + arow * D_ + d0 + 4);
            xv[0]=v0[0]; xv[1]=v0[1]; xv[2]=v0[2]; xv[3]=v0[3];
            xv[4]=v1[0]; xv[5]=v1[1]; xv[6]=v1[2]; xv[7]=v1[3];
        } else {
            #pragma unroll
            for (int j = 0; j < 8; ++j) xv[j] = 0.f;
        }
        short8 h, l;
        #pragma unroll
        for (int j = 0; j < 8; ++j){
            u16 hb = f2bf(xv[j]);
            h[j] = (short)hb;
            l[j] = (short)f2bf(xv[j] - bf2f(hb));
        }
        ah[ks] = h; al[ks] = l;
    }
    __syncthreads();

    f32x4 acc[8];
    #pragma unroll
    for (int cf = 0; cf < 8; ++cf){
        f32x4 s0 = {0.f,0.f,0.f,0.f}, s1 = {0.f,0.f,0.f,0.f}, s2 = {0.f,0.f,0.f,0.f};
        int rbase = (cf * 16 + ln) * 16;
        #pragma unroll
        for (int ks = 0; ks < 4; ++ks){
            int cu = (ks * 4 + g) ^ (ln & 7);
            short8 bh = WHs[rbase + cu];
            short8 bl = WLs[rbase + cu];
            s0 = mfma16(ah[ks], bh, s0);
            s1 = mfma16(al[ks], bh, s1);
            s2 = mfma16(ah[ks], bl, s2);
        }
        acc[cf] = s0 + s1 + s2;
    }

    if (p < 2){
        #pragma unroll
        for (int cf = 0; cf < 8; ++cf){
            #pragma unroll
            for (int i = 0; i < 4; ++i){
                long orow = (long)blockIdx.x * 64 + wave * 16 + g * 4 + i;
                int  c    = cf * 16 + ln;
                float v   = acc[cf][i];
                u16 hb = f2bf(v);
                if (p == 0){
                    Qh[orow * DP + c] = hb;
                    Ql[orow * DP + c] = f2bf(v - bf2f(hb));
                } else {
                    Kh[orow * DP + c] = hb;
                    Kl[orow * DP + c] = f2bf(v - bf2f(hb));
                }
            }
        }
    } else {
        __syncthreads();   // all W reads done; reuse smem as transpose tile
        #pragma unroll
        for (int cf = 0; cf < 8; ++cf){
            #pragma unroll
            for (int i = 0; i < 4; ++i){
                int c    = cf * 16 + ln;
                int lrow = wave * 16 + g * 4 + i;
                vtl[c * 64 + lrow] = f2bf(acc[cf][i]);
            }
        }
        __syncthreads();
        // coalesced tile-major store: Vt[((bb*64 + t0 + half)*128 + c)*32 + j]
        int c = tid >> 1, half = tid & 1;
        long n0 = ((long)blockIdx.x * 64) & 2047;
        long bb = ((long)blockIdx.x * 64) >> 11;
        long tbase = ((bb * 64 + (n0 >> 5) + half) * 128 + c) * 32;
        #pragma unroll
        for (int j = 0; j < 4; ++j){
            short8 v = *(const short8*)&vtl[c * 64 + half * 32 + j * 8];
            *(short8*)(Vt + tbase + j * 8) = v;
        }
    }
}

// ---------------------------------------------------------------------------
// Kernel 2: flash-style fused attention. QB=32, 256 threads (4 waves:
// rt=w&1 q-tile, wc=w>>1 m/e-half), grid 512 -> 2 independent blocks/CU.
// Pass A: online (max,l), dbuf K, 1 barrier/iter, 3-chain split MFMA.
// Pass B: software-pipelined (PV/attnw of tile t-1 under S-compute of t),
// all buffers double-buffered, 1 barrier/iter.
// ---------------------------------------------------------------------------
__global__ __launch_bounds__(256, 2)
void attn_kernel(const u16* __restrict__ Qh, const u16* __restrict__ Ql,
                 const u16* __restrict__ Kh, const u16* __restrict__ Kl,
                 const u16* __restrict__ Vt, const u32* __restrict__ bits,
                 float* __restrict__ outp, float* __restrict__ attnw){
    __shared__ short8 KsH[2][512];     // [buf][32 rows x 16 units] swizzled
    __shared__ short8 KsL[2][512];
    __shared__ short8 Vs [2][512];     // [buf][128 e x 4 units] swizzled
    __shared__ float  Ps [2][QB * MT]; // [buf] P tile, col ^ ((row&7)<<2)
    __shared__ float  redM[2][QB];
    __shared__ float  redL[2][QB];
    __shared__ float  smax[QB];
    __shared__ float  sinv[QB];

    int lin = blockIdx.x;
    int b   = lin & 7;                  // same-batch blocks share an XCD's L2
    int q0  = (lin >> 3) * QB;
    int tid = threadIdx.x;
    int w   = tid >> 6, lane = tid & 63;
    int rt  = w & 1, wc = w >> 1;
    int g   = lane >> 4, ln = lane & 15;

    long rowbase = (long)b * N_ + q0;
    const u16* Kbh = Kh + (long)b * N_ * DP;
    const u16* Kbl = Kl + (long)b * N_ * DP;
    const u16* Vb  = Vt + ((long)b * 64) * 4096;   // tile-major: +t*4096

    // Q A-fragments
    short8 ah[4], al[4];
    {
        const u16* qh = Qh + (rowbase + rt * 16 + ln) * DP;
        const u16* ql = Ql + (rowbase + rt * 16 + ln) * DP;
        #pragma unroll
        for (int ks = 0; ks < 4; ++ks){
            ah[ks] = *(const short8*)(qh + ks * 32 + g * 8);
            al[ks] = *(const short8*)(ql + ks * 32 + g * 8);
        }
    }

    int mrow  = wc * 16 + ln;
    int swz   = ln & 7;
    int mybit = wc * 16 + ln;
    long bitbase[4];
    #pragma unroll
    for (int i = 0; i < 4; ++i) bitbase[i] = (rowbase + rt * 16 + g * 4 + i) * 64;

    // staging slots (precomputed)
    int r0 = tid >> 4,          c0 = tid & 15;
    int slot0 = r0 * 16 + (c0 ^ (r0 & 7));
    int r1 = (tid + 256) >> 4,  c1 = tid & 15;
    int slot1 = r1 * 16 + (c1 ^ (r1 & 7));
    int e0 = tid >> 2,          m0 = tid & 3;
    int vslot0 = e0 * 4 + (m0 ^ ((e0 >> 1) & 3));
    int e1 = (tid + 256) >> 2;
    int vslot1 = e1 * 4 + (m0 ^ ((e1 >> 1) & 3));

    // ================= PASS A: online max / sum =================
    float mx[4], ls[4];
    #pragma unroll
    for (int i = 0; i < 4; ++i){ mx[i] = -1e30f; ls[i] = 0.f; }

    {   // prologue: stage K tile 0
        short8 h0 = *(const short8*)(Kbh + (long)tid * 8);
        short8 h1 = *(const short8*)(Kbh + (long)(tid + 256) * 8);
        short8 l0 = *(const short8*)(Kbl + (long)tid * 8);
        short8 l1 = *(const short8*)(Kbl + (long)(tid + 256) * 8);
        KsH[0][slot0] = h0; KsH[0][slot1] = h1;
        KsL[0][slot0] = l0; KsL[0][slot1] = l1;
        __syncthreads();
    }
    for (int t = 0; t < NT; ++t){
        int cb = t & 1;
        short8 h0, h1, l0, l1;
        if (t + 1 < NT){
            long gb = (long)(t + 1) * MT * DP;
            h0 = *(const short8*)(Kbh + gb + (long)tid * 8);
            h1 = *(const short8*)(Kbh + gb + (long)(tid + 256) * 8);
            l0 = *(const short8*)(Kbl + gb + (long)tid * 8);
            l1 = *(const short8*)(Kbl + gb + (long)(tid + 256) * 8);
        }
        u32 wd[4];
        #pragma unroll
        for (int i = 0; i < 4; ++i) wd[i] = bits[bitbase[i] + t];

        f32x4 s0 = {0.f,0.f,0.f,0.f}, s1 = {0.f,0.f,0.f,0.f}, s2 = {0.f,0.f,0.f,0.f};
        #pragma unroll
        for (int ks = 0; ks < 4; ++ks){
            int cu = (ks * 4 + g) ^ swz;
            short8 bh = KsH[cb][mrow * 16 + cu];
            short8 bl = KsL[cb][mrow * 16 + cu];
            s0 = mfma16(ah[ks], bh, s0);
            s1 = mfma16(al[ks], bh, s1);
            s2 = mfma16(ah[ks], bl, s2);
        }
        f32x4 s = s0 + s1 + s2;

        #pragma unroll
        for (int i = 0; i < 4; ++i){
            if ((wd[i] >> mybit) & 1u){
                float sv = s[i];
                float nm = fmaxf(mx[i], sv);
                ls[i] = ls[i] * __expf(mx[i] - nm) + __expf(sv - nm);
                mx[i] = nm;
            }
        }
        if (t + 1 < NT){
            int nb = cb ^ 1;
            KsH[nb][slot0] = h0; KsH[nb][slot1] = h1;
            KsL[nb][slot0] = l0; KsL[nb][slot1] = l1;
        }
        __syncthreads();
    }

    // merge across the 16 ln lanes
    #pragma unroll
    for (int i = 0; i < 4; ++i){
        #pragma unroll
        for (int sft = 1; sft < 16; sft <<= 1){
            float om = __shfl_xor(mx[i], sft, 64);
            float ol = __shfl_xor(ls[i], sft, 64);
            float nm = fmaxf(mx[i], om);
            ls[i] = ls[i] * __expf(mx[i] - nm) + ol * __expf(om - nm);
            mx[i] = nm;
        }
    }
    if (ln == 0){
        #pragma unroll
        for (int i = 0; i < 4; ++i){
            redM[wc][rt * 16 + g * 4 + i] = mx[i];
            redL[wc][rt * 16 + g * 4 + i] = ls[i];
        }
    }
    __syncthreads();
    if (tid < QB){
        float m0_ = redM[0][tid], m1_ = redM[1][tid];
        float M  = fmaxf(m0_, m1_);
        float L  = redL[0][tid] * __expf(m0_ - M) + redL[1][tid] * __expf(m1_ - M);
        smax[tid] = M;
        sinv[tid] = 1.f / L;
    }
    __syncthreads();
    float Mr[4], Ir[4];
    #pragma unroll
    for (int i = 0; i < 4; ++i){
        Mr[i] = smax[rt * 16 + g * 4 + i];
        Ir[i] = sinv[rt * 16 + g * 4 + i];
    }

    // ================= PASS B: pipelined P store + PV =================
    f32x4 acc[4];
    #pragma unroll
    for (int e = 0; e < 4; ++e) acc[e] = (f32x4){0.f, 0.f, 0.f, 0.f};

    {   // prologue: restage K tile 0
        short8 h0 = *(const short8*)(Kbh + (long)tid * 8);
        short8 h1 = *(const short8*)(Kbh + (long)(tid + 256) * 8);
        short8 l0 = *(const short8*)(Kbl + (long)tid * 8);
        short8 l1 = *(const short8*)(Kbl + (long)(tid + 256) * 8);
        KsH[0][slot0] = h0; KsH[0][slot1] = h1;
        KsL[0][slot0] = l0; KsL[0][slot1] = l1;
        __syncthreads();
    }
    for (int t = 0; t < NT; ++t){
        int cb = t & 1, pb = t & 1, ob = pb ^ 1;
        short8 h0, h1, l0, l1;
        if (t + 1 < NT){
            long gb = (long)(t + 1) * MT * DP;
            h0 = *(const short8*)(Kbh + gb + (long)tid * 8);
            h1 = *(const short8*)(Kbh + gb + (long)(tid + 256) * 8);
            l0 = *(const short8*)(Kbl + gb + (long)tid * 8);
            l1 = *(const short8*)(Kbl + gb + (long)(tid + 256) * 8);
        }
        // V tile t (linear tile-major load)
        const u16* vtile = Vb + (long)t * 4096;
        short8 v0 = *(const short8*)(vtile + (long)tid * 8);
        short8 v1 = *(const short8*)(vtile + (long)(tid + 256) * 8);

        u32 wd[4];
        #pragma unroll
        for (int i = 0; i < 4; ++i) wd[i] = bits[bitbase[i] + t];

        // S recompute (3-chain)
        f32x4 s0 = {0.f,0.f,0.f,0.f}, s1 = {0.f,0.f,0.f,0.f}, s2 = {0.f,0.f,0.f,0.f};
        #pragma unroll
        for (int ks = 0; ks < 4; ++ks){
            int cu = (ks * 4 + g) ^ swz;
            short8 bh = KsH[cb][mrow * 16 + cu];
            short8 bl = KsL[cb][mrow * 16 + cu];
            s0 = mfma16(ah[ks], bh, s0);
            s1 = mfma16(al[ks], bh, s1);
            s2 = mfma16(ah[ks], bl, s2);
        }
        f32x4 s = s0 + s1 + s2;
        float p[4];
        #pragma unroll
        for (int i = 0; i < 4; ++i)
            p[i] = ((wd[i] >> mybit) & 1u) ? __expf(s[i] - Mr[i]) * Ir[i] : 0.f;

        if (t > 0){
            // attnw store for tile t-1 (coalesced 128B rows)
            int row = tid >> 3, cg = tid & 7;
            int sw = (row & 7) << 2;
            f32x4 pv = *(const f32x4*)&Ps[ob][row * 32 + ((cg * 4) ^ sw)];
            *(f32x4*)(attnw + (rowbase + row) * N_ + (long)(t - 1) * MT + cg * 4) = pv;
            // PV for tile t-1
            int prow = rt * 16 + ln;
            int sx = (prow & 7) << 2;
            f32x4 p0 = *(const f32x4*)&Ps[ob][prow * 32 + ((g * 8)     ^ sx)];
            f32x4 p1 = *(const f32x4*)&Ps[ob][prow * 32 + ((g * 8 + 4) ^ sx)];
            short8 pa;
            #pragma unroll
            for (int j = 0; j < 4; ++j){
                pa[j]     = (short)f2bf(p0[j]);
                pa[4 + j] = (short)f2bf(p1[j]);
            }
            #pragma unroll
            for (int ef = 0; ef < 4; ++ef){
                int e = wc * 64 + ef * 16 + ln;
                short8 vb = Vs[ob][e * 4 + (g ^ ((e >> 1) & 3))];
                acc[ef] = mfma16(pa, vb, acc[ef]);
            }
        }
        // write P tile t
        #pragma unroll
        for (int i = 0; i < 4; ++i){
            int prow = rt * 16 + g * 4 + i;
            Ps[pb][prow * 32 + (mybit ^ ((prow & 7) << 2))] = p[i];
        }
        // write staged K (t+1) and V (t)
        if (t + 1 < NT){
            int nb = cb ^ 1;
            KsH[nb][slot0] = h0; KsH[nb][slot1] = h1;
            KsL[nb][slot0] = l0; KsL[nb][slot1] = l1;
        }
        Vs[cb][vslot0] = v0; Vs[cb][vslot1] = v1;
        __syncthreads();
    }
    {   // epilogue: tile NT-1
        int lb = (NT - 1) & 1;
        int row = tid >> 3, cg = tid & 7;
        int sw = (row & 7) << 2;
        f32x4 pv = *(const f32x4*)&Ps[lb][row * 32 + ((cg * 4) ^ sw)];
        *(f32x4*)(attnw + (rowbase + row) * N_ + (long)(NT - 1) * MT + cg * 4) = pv;
        int prow = rt * 16 + ln;
        int sx = (prow & 7) << 2;
        f32x4 p0 = *(const f32x4*)&Ps[lb][prow * 32 + ((g * 8)     ^ sx)];
        f32x4 p1 = *(const f32x4*)&Ps[lb][prow * 32 + ((g * 8 + 4) ^ sx)];
        short8 pa;
        #pragma unroll
        for (int j = 0; j < 4; ++j){
            pa[j]     = (short)f2bf(p0[j]);
            pa[4 + j] = (short)f2bf(p1[j]);
        }
        #pragma unroll
        for (int ef = 0; ef < 4; ++ef){
            int e = wc * 64 + ef * 16 + ln;
            short8 vb = Vs[lb][e * 4 + (g ^ ((e >> 1) & 3))];
            acc[ef] = mfma16(pa, vb, acc[ef]);
        }
    }

    // ---- output store ----
    #pragma unroll
    for (int ef = 0; ef < 4; ++ef){
        #pragma unroll
        for (int i = 0; i < 4; ++i){
            int col = wc * 64 + ef * 16 + ln;
            if (col < D_)
                outp[(rowbase + rt * 16 + g * 4 + i) * D_ + col] = acc[ef][i];
        }
    }
}

// ---------------------------------------------------------------------------
extern "C" void kernel_launch(void* const* d_in, const int* in_sizes, int n_in,
                              void* d_out, int out_size, void* d_ws, size_t ws_size,
                              hipStream_t stream){
    const float* x1   = (const float*)d_in[0];
    const float* x2   = (const float*)d_in[1];
    const int*   mask = (const int*)d_in[2];
    const float* Wq   = (const float*)d_in[3];
    const float* Wk   = (const float*)d_in[4];
    const float* Wv   = (const float*)d_in[5];

    float* outp  = (float*)d_out;
    float* attnw = outp + (size_t)B_ * N_ * D_;   // outputs concatenated flat

    const size_t TEN = (size_t)B_ * N_ * DP;      // 2,097,152
    u32* bits = (u32*)d_ws;                       // B*N*64 u32 = 4 MB
    u16* Qh   = (u16*)(bits + (size_t)B_ * N_ * 64);
    u16* Ql   = Qh + TEN;
    u16* Kh   = Ql + TEN;
    u16* Kl   = Kh + TEN;
    u16* Vt   = Kl + TEN;                         // tile-major [B][64][128][32]
    u16* Wth  = Vt + TEN;
    u16* Wtl  = Wth + (size_t)3 * DP * DP;

    hipLaunchKernelGGL(wprep, dim3(3), dim3(256), 0, stream, Wq, Wk, Wv, Wth, Wtl);
    hipLaunchKernelGGL(maskprep, dim3((B_ * N_) / 4), dim3(256), 0, stream, mask, bits);
    hipLaunchKernelGGL(proj_kernel, dim3((B_ * N_) / 64, 3), dim3(256), 0, stream,
                       x1, x2, Wth, Wtl, Qh, Ql, Kh, Kl, Vt);
    hipLaunchKernelGGL(attn_kernel, dim3((B_ * N_) / QB), dim3(256), 0, stream,
                       Qh, Ql, Kh, Kl, Vt, bits, outp, attnw);
}

// Round 8
// 200.132 us; speedup vs baseline: 1.9429x; 1.1175x over previous
//
#include <hip/hip_runtime.h>
#include <stdint.h>

#define B_ 8
#define N_ 2048
#define D_ 120
#define DP 128          // D padded to 128 (k-dim of MFMA)
#define QB 32           // q rows per attention block
#define MT 32           // m-tile (k/v rows per step)
#define NT (N_ / MT)    // 64 steps

typedef __attribute__((ext_vector_type(8))) short short8;
typedef __attribute__((ext_vector_type(4))) float f32x4;
typedef __attribute__((ext_vector_type(4))) float float4v;
typedef __attribute__((ext_vector_type(2))) unsigned int u32x2;
typedef unsigned short u16;
typedef unsigned int u32;

__device__ __forceinline__ u16 f2bf(float f){
    union { float f; uint32_t u; } v; v.f = f;
    uint32_t u = v.u;
    return (u16)((u + 0x7fffu + ((u >> 16) & 1u)) >> 16);
}
__device__ __forceinline__ float bf2f(u16 h){
    union { uint32_t u; float f; } v; v.u = ((uint32_t)h) << 16; return v.f;
}
__device__ __forceinline__ f32x4 mfma16(short8 a, short8 b, f32x4 c){
    return __builtin_amdgcn_mfma_f32_16x16x32_bf16(a, b, c, 0, 0, 0);
}

// LDS-only barrier: drain LDS ops, do NOT drain vmcnt (no cross-thread global
// data inside the loop; attnw stores have no in-kernel readers). This removes
// the compiler's vmcnt(0) drain that serialized every iteration.
__device__ __forceinline__ void bar_lds(){
    asm volatile("s_waitcnt lgkmcnt(0)\n\ts_barrier" ::: "memory");
}

// ---------------------------------------------------------------------------
// Kernel 0: transpose + split weights (bf16 hi/lo), zero-padded to 128x128.
// ---------------------------------------------------------------------------
__global__ void wprep(const float* __restrict__ Wq, const float* __restrict__ Wk,
                      const float* __restrict__ Wv,
                      u16* __restrict__ Wth, u16* __restrict__ Wtl){
    int p = blockIdx.x;
    const float* W = (p == 0) ? Wq : (p == 1 ? Wk : Wv);
    float scale = (p == 0) ? 0.09128709291752768f : 1.0f;  // 1/sqrt(120)
    for (int idx = threadIdx.x; idx < DP * DP; idx += blockDim.x){
        int c = idx & (DP - 1);
        int d = idx >> 7;
        float w = (c < D_ && d < D_) ? W[d * D_ + c] * scale : 0.f;
        u16 hi = f2bf(w);
        Wth[p * DP * DP + c * DP + d] = hi;
        Wtl[p * DP * DP + c * DP + d] = f2bf(w - bf2f(hi));
    }
}

// ---------------------------------------------------------------------------
// Kernel 0b: mask -> bitmask (2048 int32 -> 64 u32 per row), coalesced.
// ---------------------------------------------------------------------------
__global__ __launch_bounds__(256)
void maskprep(const int* __restrict__ mask, u32* __restrict__ bits){
    int wid  = (blockIdx.x * 256 + threadIdx.x) >> 6;
    int lane = threadIdx.x & 63;
    long base = (long)wid * N_;
    u32 myw = 0;
    #pragma unroll
    for (int it = 0; it < 32; ++it){
        int v = mask[base + it * 64 + lane];
        unsigned long long bb = __ballot(v != 0);
        if ((lane >> 1) == it)
            myw = (lane & 1) ? (u32)(bb >> 32) : (u32)bb;
    }
    bits[((long)wid << 6) + lane] = myw;
}

// ---------------------------------------------------------------------------
// Kernel 1: projections. W (hi+lo) staged in swizzled LDS; V written
// tile-major [b][t][e][32] via LDS transpose (coalesced stores).
// ---------------------------------------------------------------------------
__global__ __launch_bounds__(256, 2)
void proj_kernel(const float* __restrict__ x1, const float* __restrict__ x2,
                 const u16* __restrict__ Wth, const u16* __restrict__ Wtl,
                 u16* __restrict__ Qh, u16* __restrict__ Ql,
                 u16* __restrict__ Kh, u16* __restrict__ Kl,
                 u16* __restrict__ Vt){
    __shared__ short8 smem8[4096];          // 64 KB: WH[2048] | WL[2048]
    short8* WHs = smem8;
    short8* WLs = smem8 + 2048;
    u16* vtl = (u16*)smem8;                 // reused after compute: [128][64]

    int p    = blockIdx.y;
    const float* x = (p == 0) ? x1 : x2;
    int tid  = threadIdx.x;
    int wave = tid >> 6, lane = tid & 63;
    int g = lane >> 4, ln = lane & 15;
    long arow = (long)blockIdx.x * 64 + wave * 16 + ln;

    const u16* wh = Wth + p * DP * DP;
    const u16* wl = Wtl + p * DP * DP;
    #pragma unroll
    for (int j = 0; j < 8; ++j){
        int u = tid + j * 256;
        int row = u >> 4, cu = u & 15;
        int slot = row * 16 + (cu ^ (row & 7));
        WHs[slot] = *(const short8*)(wh + (long)u * 8);
        WLs[slot] = *(const short8*)(wl + (long)u * 8);
    }

    short8 ah[4], al[4];
    #pragma unroll
    for (int ks = 0; ks < 4; ++ks){
        int d0 = ks * 32 + g * 8;
        float xv[8];
        if (d0 < D_){
            float4v v0 = *(const float4v*)(x + arow * D_ + d0);
            float4v v1 = *(const float4v*)(x + arow * D_ + d0 + 4);
            xv[0]=v0[0]; xv[1]=v0[1]; xv[2]=v0[2]; xv[3]=v0[3];
            xv[4]=v1[0]; xv[5]=v1[1]; xv[6]=v1[2]; xv[7]=v1[3];
        } else {
            #pragma unroll
            for (int j = 0; j < 8; ++j) xv[j] = 0.f;
        }
        short8 h, l;
        #pragma unroll
        for (int j = 0; j < 8; ++j){
            u16 hb = f2bf(xv[j]);
            h[j] = (short)hb;
            l[j] = (short)f2bf(xv[j] - bf2f(hb));
        }
        ah[ks] = h; al[ks] = l;
    }
    __syncthreads();

    f32x4 acc[8];
    #pragma unroll
    for (int cf = 0; cf < 8; ++cf){
        f32x4 s0 = {0.f,0.f,0.f,0.f}, s1 = {0.f,0.f,0.f,0.f}, s2 = {0.f,0.f,0.f,0.f};
        int rbase = (cf * 16 + ln) * 16;
        #pragma unroll
        for (int ks = 0; ks < 4; ++ks){
            int cu = (ks * 4 + g) ^ (ln & 7);
            short8 bh = WHs[rbase + cu];
            short8 bl = WLs[rbase + cu];
            s0 = mfma16(ah[ks], bh, s0);
            s1 = mfma16(al[ks], bh, s1);
            s2 = mfma16(ah[ks], bl, s2);
        }
        acc[cf] = s0 + s1 + s2;
    }

    if (p < 2){
        #pragma unroll
        for (int cf = 0; cf < 8; ++cf){
            #pragma unroll
            for (int i = 0; i < 4; ++i){
                long orow = (long)blockIdx.x * 64 + wave * 16 + g * 4 + i;
                int  c    = cf * 16 + ln;
                float v   = acc[cf][i];
                u16 hb = f2bf(v);
                if (p == 0){
                    Qh[orow * DP + c] = hb;
                    Ql[orow * DP + c] = f2bf(v - bf2f(hb));
                } else {
                    Kh[orow * DP + c] = hb;
                    Kl[orow * DP + c] = f2bf(v - bf2f(hb));
                }
            }
        }
    } else {
        __syncthreads();
        #pragma unroll
        for (int cf = 0; cf < 8; ++cf){
            #pragma unroll
            for (int i = 0; i < 4; ++i){
                int c    = cf * 16 + ln;
                int lrow = wave * 16 + g * 4 + i;
                vtl[c * 64 + lrow] = f2bf(acc[cf][i]);
            }
        }
        __syncthreads();
        int c = tid >> 1, half = tid & 1;
        long n0 = ((long)blockIdx.x * 64) & 2047;
        long bb = ((long)blockIdx.x * 64) >> 11;
        long tbase = ((bb * 64 + (n0 >> 5) + half) * 128 + c) * 32;
        #pragma unroll
        for (int j = 0; j < 4; ++j){
            short8 v = *(const short8*)&vtl[c * 64 + half * 32 + j * 8];
            *(short8*)(Vt + tbase + j * 8) = v;
        }
    }
}

// ---------------------------------------------------------------------------
// Kernel 2: flash-style fused attention, raw-barrier pipeline.
// QB=32, 256 threads (4 waves), grid 512 -> 2 blocks/CU.
// 2-deep register prefetch (K: t+3, V: t+2) + LDS-only barriers so no vmcnt
// drain ever sits on the loop critical path.
// ---------------------------------------------------------------------------
#define ISSUE_K(P, T) do{ long gb_ = (long)(T) * MT * DP;                         \
    P##h0 = *(const short8*)(Kbh + gb_ + (long)tid * 8);                          \
    P##h1 = *(const short8*)(Kbh + gb_ + (long)(tid + 256) * 8);                  \
    P##l0 = *(const short8*)(Kbl + gb_ + (long)tid * 8);                          \
    P##l1 = *(const short8*)(Kbl + gb_ + (long)(tid + 256) * 8); }while(0)

#define WRITE_K(BUF, P) do{                                                       \
    KsH[BUF][slot0] = P##h0; KsH[BUF][slot1] = P##h1;                             \
    KsL[BUF][slot0] = P##l0; KsL[BUF][slot1] = P##l1; }while(0)

#define ISSUE_V(P, T) do{ const u16* vt_ = Vb + (long)(T) * 4096;                 \
    P##0 = *(const short8*)(vt_ + (long)tid * 8);                                 \
    P##1 = *(const short8*)(vt_ + (long)(tid + 256) * 8); }while(0)

#define WRITE_V(BUF, P) do{ Vs[BUF][vslot0] = P##0; Vs[BUF][vslot1] = P##1; }while(0)

#define COMPUTE_S(CB, SD) do{                                                     \
    f32x4 s0_ = {0.f,0.f,0.f,0.f}, s1_ = s0_, s2_ = s0_;                          \
    __builtin_amdgcn_s_setprio(1);                                                \
    _Pragma("unroll") for (int ks_ = 0; ks_ < 4; ++ks_){                          \
        int cu_ = (ks_ * 4 + g) ^ swz;                                            \
        short8 bh_ = KsH[CB][mrow * 16 + cu_];                                    \
        short8 bl_ = KsL[CB][mrow * 16 + cu_];                                    \
        s0_ = mfma16(ah[ks_], bh_, s0_);                                          \
        s1_ = mfma16(al[ks_], bh_, s1_);                                          \
        s2_ = mfma16(ah[ks_], bl_, s2_); }                                        \
    __builtin_amdgcn_s_setprio(0);                                                \
    SD = s0_ + s1_ + s2_; }while(0)

#define ONLINE(W0, W1, W2, W3, S) do{ u32 ww_[4] = {W0, W1, W2, W3};              \
    _Pragma("unroll") for (int i = 0; i < 4; ++i){                                \
        float sv_ = ((ww_[i] >> mybit) & 1u) ? (S)[i] : -3.0e38f;                 \
        if (__any(sv_ > mx[i])){                                                  \
            float nm_ = fmaxf(mx[i], sv_);                                        \
            ls[i] *= __expf(mx[i] - nm_); mx[i] = nm_;                            \
        }                                                                         \
        ls[i] += __expf(sv_ - mx[i]); } }while(0)

#define PNORM(W0, W1, W2, W3, S, PD) do{ u32 ww_[4] = {W0, W1, W2, W3};           \
    _Pragma("unroll") for (int i = 0; i < 4; ++i)                                 \
        PD[i] = ((ww_[i] >> mybit) & 1u) ? __expf((S)[i] - Mr[i]) * Ir[i] : 0.f;  \
    }while(0)

#define PWRITE(PB, PD) do{ _Pragma("unroll") for (int i = 0; i < 4; ++i){         \
    int prow_ = rt * 16 + g * 4 + i;                                              \
    Ps[PB][prow_ * 32 + (mybit ^ ((prow_ & 7) << 2))] = PD[i]; } }while(0)

#define PV_STEP(PB, VBUF, TPREV) do{                                              \
    int row_ = tid >> 3, cg_ = tid & 7;                                           \
    int sw_ = (row_ & 7) << 2;                                                    \
    f32x4 pv_ = *(const f32x4*)&Ps[PB][row_ * 32 + ((cg_ * 4) ^ sw_)];            \
    *(f32x4*)(attnw + (rowbase + row_) * N_ + (long)(TPREV) * MT + cg_ * 4) = pv_;\
    int prow_ = rt * 16 + ln, sx_ = (prow_ & 7) << 2;                             \
    f32x4 pq0_ = *(const f32x4*)&Ps[PB][prow_ * 32 + ((g * 8) ^ sx_)];            \
    f32x4 pq1_ = *(const f32x4*)&Ps[PB][prow_ * 32 + (((g * 8) + 4) ^ sx_)];      \
    union { u32 w[4]; short8 s8; } pu_;                                           \
    asm("v_cvt_pk_bf16_f32 %0, %1, %2" : "=v"(pu_.w[0]) : "v"(pq0_[0]), "v"(pq0_[1])); \
    asm("v_cvt_pk_bf16_f32 %0, %1, %2" : "=v"(pu_.w[1]) : "v"(pq0_[2]), "v"(pq0_[3])); \
    asm("v_cvt_pk_bf16_f32 %0, %1, %2" : "=v"(pu_.w[2]) : "v"(pq1_[0]), "v"(pq1_[1])); \
    asm("v_cvt_pk_bf16_f32 %0, %1, %2" : "=v"(pu_.w[3]) : "v"(pq1_[2]), "v"(pq1_[3])); \
    short8 pa_ = pu_.s8;                                                          \
    __builtin_amdgcn_s_setprio(1);                                                \
    _Pragma("unroll") for (int ef_ = 0; ef_ < 4; ++ef_){                          \
        int e_ = wc * 64 + ef_ * 16 + ln;                                         \
        short8 vb_ = Vs[VBUF][e_ * 4 + (g ^ ((e_ >> 1) & 3))];                    \
        acc[ef_] = mfma16(pa_, vb_, acc[ef_]); }                                  \
    __builtin_amdgcn_s_setprio(0); }while(0)

__global__ __launch_bounds__(256, 2)
void attn_kernel(const u16* __restrict__ Qh, const u16* __restrict__ Ql,
                 const u16* __restrict__ Kh, const u16* __restrict__ Kl,
                 const u16* __restrict__ Vt, const u32* __restrict__ bits,
                 float* __restrict__ outp, float* __restrict__ attnw){
    __shared__ short8 KsH[2][512];     // [buf][32 rows x 16 units] swizzled
    __shared__ short8 KsL[2][512];
    __shared__ short8 Vs [2][512];     // [buf][128 e x 4 units] swizzled
    __shared__ float  Ps [2][QB * MT]; // [buf] P tile, col ^ ((row&7)<<2)
    __shared__ float  redM[2][QB];
    __shared__ float  redL[2][QB];
    __shared__ float  smax[QB];
    __shared__ float  sinv[QB];

    int lin = blockIdx.x;
    int b   = lin & 7;                  // batch == XCD (round-robin dispatch)
    int q0  = (lin >> 3) * QB;
    int tid = threadIdx.x;
    int w   = tid >> 6, lane = tid & 63;
    int rt  = w & 1, wc = w >> 1;
    int g   = lane >> 4, ln = lane & 15;

    long rowbase = (long)b * N_ + q0;
    const u16* Kbh = Kh + (long)b * N_ * DP;
    const u16* Kbl = Kl + (long)b * N_ * DP;
    const u16* Vb  = Vt + ((long)b * 64) * 4096;   // tile-major: +t*4096

    // Q A-fragments
    short8 ah[4], al[4];
    {
        const u16* qh = Qh + (rowbase + rt * 16 + ln) * DP;
        const u16* ql = Ql + (rowbase + rt * 16 + ln) * DP;
        #pragma unroll
        for (int ks = 0; ks < 4; ++ks){
            ah[ks] = *(const short8*)(qh + ks * 32 + g * 8);
            al[ks] = *(const short8*)(ql + ks * 32 + g * 8);
        }
    }

    int mrow  = wc * 16 + ln;
    int swz   = ln & 7;
    int mybit = wc * 16 + ln;
    long bitbase[4];
    #pragma unroll
    for (int i = 0; i < 4; ++i) bitbase[i] = (rowbase + rt * 16 + g * 4 + i) * 64;

    int r0 = tid >> 4,          c0 = tid & 15;
    int slot0 = r0 * 16 + (c0 ^ (r0 & 7));
    int r1 = (tid + 256) >> 4,  c1 = tid & 15;
    int slot1 = r1 * 16 + (c1 ^ (r1 & 7));
    int e0 = tid >> 2,          m0 = tid & 3;
    int vslot0 = e0 * 4 + (m0 ^ ((e0 >> 1) & 3));
    int e1 = (tid + 256) >> 2;
    int vslot1 = e1 * 4 + (m0 ^ ((e1 >> 1) & 3));

    // prefetch register sets (statically named — rule #20)
    short8 kAh0, kAh1, kAl0, kAl1;
    short8 kBh0, kBh1, kBl0, kBl1;
    short8 vA0, vA1, vB0, vB1;

    // ================= PASS A: max + sum (lazy online) =================
    float mx[4], ls[4];
    #pragma unroll
    for (int i = 0; i < 4; ++i){ mx[i] = -1e30f; ls[i] = 0.f; }

    {   // prologue: direct-stage K0, prefetch K1/K2
        short8 h0 = *(const short8*)(Kbh + (long)tid * 8);
        short8 h1 = *(const short8*)(Kbh + (long)(tid + 256) * 8);
        short8 l0 = *(const short8*)(Kbl + (long)tid * 8);
        short8 l1 = *(const short8*)(Kbl + (long)(tid + 256) * 8);
        ISSUE_K(kA, 1);
        ISSUE_K(kB, 2);
        KsH[0][slot0] = h0; KsH[0][slot1] = h1;
        KsL[0][slot0] = l0; KsL[0][slot1] = l1;
        bar_lds();
    }
    for (int t = 0; t < NT; t += 2){
        u32x2 wd[4];
        #pragma unroll
        for (int i = 0; i < 4; ++i) wd[i] = *(const u32x2*)(bits + bitbase[i] + t);

        f32x4 s;
        COMPUTE_S(0, s);
        ONLINE(wd[0][0], wd[1][0], wd[2][0], wd[3][0], s);
        WRITE_K(1, kA);                       // tile t+1 (issued >=2 iters ago)
        if (t + 3 < NT) ISSUE_K(kA, t + 3);
        bar_lds();

        COMPUTE_S(1, s);
        ONLINE(wd[0][1], wd[1][1], wd[2][1], wd[3][1], s);
        if (t + 2 < NT) WRITE_K(0, kB);       // tile t+2
        if (t + 4 < NT) ISSUE_K(kB, t + 4);
        bar_lds();
    }

    // merge across the 16 ln lanes
    #pragma unroll
    for (int i = 0; i < 4; ++i){
        #pragma unroll
        for (int sft = 1; sft < 16; sft <<= 1){
            float om = __shfl_xor(mx[i], sft, 64);
            float ol = __shfl_xor(ls[i], sft, 64);
            float nm = fmaxf(mx[i], om);
            ls[i] = ls[i] * __expf(mx[i] - nm) + ol * __expf(om - nm);
            mx[i] = nm;
        }
    }
    if (ln == 0){
        #pragma unroll
        for (int i = 0; i < 4; ++i){
            redM[wc][rt * 16 + g * 4 + i] = mx[i];
            redL[wc][rt * 16 + g * 4 + i] = ls[i];
        }
    }
    __syncthreads();
    if (tid < QB){
        float m0_ = redM[0][tid], m1_ = redM[1][tid];
        float M  = fmaxf(m0_, m1_);
        float L  = redL[0][tid] * __expf(m0_ - M) + redL[1][tid] * __expf(m1_ - M);
        smax[tid] = M;
        sinv[tid] = 1.f / L;
    }
    __syncthreads();
    float Mr[4], Ir[4];
    #pragma unroll
    for (int i = 0; i < 4; ++i){
        Mr[i] = smax[rt * 16 + g * 4 + i];
        Ir[i] = sinv[rt * 16 + g * 4 + i];
    }

    // ================= PASS B: pipelined P store + PV =================
    f32x4 acc[4];
    #pragma unroll
    for (int e = 0; e < 4; ++e) acc[e] = (f32x4){0.f, 0.f, 0.f, 0.f};

    {   // prologue: restage K0; prefetch K1/K2 and V0/V1
        short8 h0 = *(const short8*)(Kbh + (long)tid * 8);
        short8 h1 = *(const short8*)(Kbh + (long)(tid + 256) * 8);
        short8 l0 = *(const short8*)(Kbl + (long)tid * 8);
        short8 l1 = *(const short8*)(Kbl + (long)(tid + 256) * 8);
        ISSUE_K(kA, 1);
        ISSUE_K(kB, 2);
        ISSUE_V(vA, 0);
        ISSUE_V(vB, 1);
        KsH[0][slot0] = h0; KsH[0][slot1] = h1;
        KsL[0][slot0] = l0; KsL[0][slot1] = l1;
        bar_lds();
    }
    for (int t = 0; t < NT; t += 2){
        u32x2 wd[4];
        #pragma unroll
        for (int i = 0; i < 4; ++i) wd[i] = *(const u32x2*)(bits + bitbase[i] + t);

        // even sub-iter: tile t (Ks[0])
        f32x4 s;
        COMPUTE_S(0, s);
        float pe[4];
        PNORM(wd[0][0], wd[1][0], wd[2][0], wd[3][0], s, pe);
        if (t > 0) PV_STEP(1, 1, t - 1);      // attnw + PV for tile t-1
        PWRITE(0, pe);                        // P tile t
        WRITE_K(1, kA);                       // K tile t+1
        if (t + 3 < NT) ISSUE_K(kA, t + 3);
        WRITE_V(0, vA);                       // V tile t
        if (t + 2 < NT) ISSUE_V(vA, t + 2);
        bar_lds();

        // odd sub-iter: tile t+1 (Ks[1])
        COMPUTE_S(1, s);
        float po[4];
        PNORM(wd[0][1], wd[1][1], wd[2][1], wd[3][1], s, po);
        PV_STEP(0, 0, t);                     // attnw + PV for tile t
        PWRITE(1, po);                        // P tile t+1
        if (t + 2 < NT) WRITE_K(0, kB);       // K tile t+2
        if (t + 4 < NT) ISSUE_K(kB, t + 4);
        WRITE_V(1, vB);                       // V tile t+1
        if (t + 3 < NT) ISSUE_V(vB, t + 3);
        bar_lds();
    }
    // epilogue: tile NT-1 (odd -> Ps[1], Vs[1])
    PV_STEP(1, 1, NT - 1);

    // ---- output store ----
    #pragma unroll
    for (int ef = 0; ef < 4; ++ef){
        #pragma unroll
        for (int i = 0; i < 4; ++i){
            int col = wc * 64 + ef * 16 + ln;
            if (col < D_)
                outp[(rowbase + rt * 16 + g * 4 + i) * D_ + col] = acc[ef][i];
        }
    }
}

// ---------------------------------------------------------------------------
extern "C" void kernel_launch(void* const* d_in, const int* in_sizes, int n_in,
                              void* d_out, int out_size, void* d_ws, size_t ws_size,
                              hipStream_t stream){
    const float* x1   = (const float*)d_in[0];
    const float* x2   = (const float*)d_in[1];
    const int*   mask = (const int*)d_in[2];
    const float* Wq   = (const float*)d_in[3];
    const float* Wk   = (const float*)d_in[4];
    const float* Wv   = (const float*)d_in[5];

    float* outp  = (float*)d_out;
    float* attnw = outp + (size_t)B_ * N_ * D_;   // outputs concatenated flat

    const size_t TEN = (size_t)B_ * N_ * DP;      // 2,097,152
    u32* bits = (u32*)d_ws;                       // B*N*64 u32 = 4 MB
    u16* Qh   = (u16*)(bits + (size_t)B_ * N_ * 64);
    u16* Ql   = Qh + TEN;
    u16* Kh   = Ql + TEN;
    u16* Kl   = Kh + TEN;
    u16* Vt   = Kl + TEN;                         // tile-major [B][64][128][32]
    u16* Wth  = Vt + TEN;
    u16* Wtl  = Wth + (size_t)3 * DP * DP;

    hipLaunchKernelGGL(wprep, dim3(3), dim3(256), 0, stream, Wq, Wk, Wv, Wth, Wtl);
    hipLaunchKernelGGL(maskprep, dim3((B_ * N_) / 4), dim3(256), 0, stream, mask, bits);
    hipLaunchKernelGGL(proj_kernel, dim3((B_ * N_) / 64, 3), dim3(256), 0, stream,
                       x1, x2, Wth, Wtl, Qh, Ql, Kh, Kl, Vt);
    hipLaunchKernelGGL(attn_kernel, dim3((B_ * N_) / QB), dim3(256), 0, stream,
                       Qh, Ql, Kh, Kl, Vt, bits, outp, attnw);
}